// Round 2
// baseline (169.507 us; speedup 1.0000x reference)
//
#include <hip/hip_runtime.h>
#include <hip/hip_bf16.h>
#include <stdint.h>

// NT-Xent loss, B=4096, D=256, T=0.5, eps=1e-8.
// loss_r = log(sum_{c!=r} exp(2*dot(zn_r,zn_c))) - 2*dot(zin_r, zjn_r); out = mean.
// Trick: store zn_s = zn * sqrt(2*log2e) in bf16, so MFMA acc = 2*log2e*dot and
// exp(2*dot) = exp2(acc) directly. Diagonal accumulated unconditionally, subtracted
// in the finish kernel via exp2(diag) with diag = sum(zn_s_bf16^2) (exact bf16 self-dot).

#define BROWS 4096
#define DIM   256
#define N2    8192

typedef __attribute__((ext_vector_type(4))) float          f32x4;
typedef __attribute__((ext_vector_type(8))) short          s16x8;
typedef __attribute__((ext_vector_type(4))) unsigned short u16x4;

#define K_EXP  2.8853900817779268f   /* 2*log2(e) */
#define S_EXP  1.6986436597467051f   /* sqrt(2*log2(e)) */
#define LN2    0.6931471805599453f

__device__ inline unsigned short f2bf(float f) {
    uint32_t b = __float_as_uint(f);
    b += 0x7fffu + ((b >> 16) & 1u);   // RNE
    return (unsigned short)(b >> 16);
}
__device__ inline float bf2f(unsigned short u) {
    return __uint_as_float(((uint32_t)u) << 16);
}

__device__ inline void gload_lds16(const void* g, void* l) {
    __builtin_amdgcn_global_load_lds(
        (const __attribute__((address_space(1))) uint32_t*)g,
        (__attribute__((address_space(3))) uint32_t*)l, 16, 0, 0);
}

__device__ inline float wave_reduce(float v) {
    #pragma unroll
    for (int m = 1; m < 64; m <<= 1) v += __shfl_xor(v, m);
    return v;
}

// ---- K1: fused normalize (both views) + positive-pair exponent + diag self-dot ----
// One wave per pair index i: reads zi[i], zj[i]; writes zn_s rows i and i+4096,
// diag[i], diag[i+4096], posv[i].
__global__ __launch_bounds__(256) void k_norm_pos(const float* __restrict__ zi,
                                                  const float* __restrict__ zj,
                                                  unsigned short* __restrict__ zn,
                                                  float* __restrict__ diag,
                                                  float* __restrict__ posv) {
    int i    = blockIdx.x * 4 + (threadIdx.x >> 6);
    int lane = threadIdx.x & 63;
    f32x4 a = *(const f32x4*)(zi + (size_t)i * DIM + lane * 4);
    f32x4 b = *(const f32x4*)(zj + (size_t)i * DIM + lane * 4);
    float ssa = a[0]*a[0] + a[1]*a[1] + a[2]*a[2] + a[3]*a[3];
    float ssb = b[0]*b[0] + b[1]*b[1] + b[2]*b[2] + b[3]*b[3];
    float dab = a[0]*b[0] + a[1]*b[1] + a[2]*b[2] + a[3]*b[3];
    ssa = wave_reduce(ssa);
    ssb = wave_reduce(ssb);
    dab = wave_reduce(dab);
    float na = 1.0f / fmaxf(sqrtf(ssa), 1e-8f);
    float nb = 1.0f / fmaxf(sqrtf(ssb), 1e-8f);
    if (lane == 0) posv[i] = 2.0f * dab * na * nb;   // natural-log exponent of pos pair

    float sa = na * S_EXP, sb = nb * S_EXP;
    u16x4 oa, ob;
    float da = 0.0f, db = 0.0f;
    #pragma unroll
    for (int k = 0; k < 4; ++k) {
        unsigned short ua = f2bf(a[k] * sa);
        unsigned short ub = f2bf(b[k] * sb);
        oa[k] = ua; ob[k] = ub;
        float fa = bf2f(ua), fb = bf2f(ub);
        da += fa * fa; db += fb * fb;
    }
    *(u16x4*)(zn + (size_t)i * DIM + lane * 4)           = oa;
    *(u16x4*)(zn + (size_t)(i + BROWS) * DIM + lane * 4) = ob;
    da = wave_reduce(da);
    db = wave_reduce(db);
    if (lane == 0) { diag[i] = da; diag[i + BROWS] = db; }
}

// ---- K2: fused sim GEMM + exp2 + row-sum (diagonal NOT masked) ----
// Block: 512 thr = 8 waves; 256 rows x 512 cols per block; grid = 32*16 = 512.
// Wave owns 32 rows (2 row-tiles of 16), A-frags pinned (64 VGPRs, K=256).
// B double-buffered in LDS: 2 x (64 cols x 256 K), K-major subtiled:
//   byte = buf*32768 + kc*4096 + g*1024 + col*16  holds zn[colbase+s*64+col][kc*32+g*8..+8]
__global__ __launch_bounds__(512, 4) void k_simsum(const unsigned short* __restrict__ zn,
                                                   float* __restrict__ partial) {
    __shared__ unsigned short lds[2][64 * DIM];   // 2 x 32 KB
    int bid = blockIdx.x;
    int rb = bid & 31;        // 32 row-blocks of 256
    int cc = bid >> 5;        // 16 col-chunks of 512
    int rowbase = rb * 256;
    int colbase = cc * 512;
    int tid = threadIdx.x, lane = tid & 63, w = tid >> 6;   // w in 0..7
    int cl = lane & 15, g = lane >> 4;

    // A fragments: lane holds zn[rowbase + w*32 + rt*16 + cl][kc*32 + g*8 .. +8]
    s16x8 afrag[2][8];
    #pragma unroll
    for (int rt = 0; rt < 2; ++rt) {
        int row = rowbase + w * 32 + rt * 16 + cl;
        const unsigned short* ap = zn + (size_t)row * DIM + g * 8;
        #pragma unroll
        for (int kc = 0; kc < 8; ++kc)
            afrag[rt][kc] = *(const s16x8*)(ap + kc * 32);
    }

    float pp[2][4];
    #pragma unroll
    for (int rt = 0; rt < 2; ++rt)
        #pragma unroll
        for (int r = 0; r < 4; ++r) pp[rt][r] = 0.0f;

    // stage 64 cols x 256 K into lds[buf]; 512 lanes x 16 B x 4 issues = 32 KB
    auto stage = [&](int buf, int s) {
        int crow = colbase + s * 64 + lane;
        const unsigned short* gsrc = zn + (size_t)crow * DIM + (w & 3) * 8;
        char* ldst = (char*)&lds[buf][0] + (w >> 2) * 16384 + (w & 3) * 1024;
        #pragma unroll
        for (int j = 0; j < 4; ++j)
            gload_lds16(gsrc + ((w >> 2) * 4 + j) * 32, ldst + j * 4096);
    };

    stage(0, 0);
    __syncthreads();   // prologue: buf0 ready

    for (int s = 0; s < 8; ++s) {
        int cur = s & 1;
        if (s < 7) stage(cur ^ 1, s + 1);   // issue next-tile loads BEFORE compute

        const char* lbase = (const char*)&lds[cur][0];
        #pragma unroll
        for (int ct = 0; ct < 4; ++ct) {
            f32x4 acc[2];
            acc[0] = (f32x4){0.f, 0.f, 0.f, 0.f};
            acc[1] = (f32x4){0.f, 0.f, 0.f, 0.f};
            #pragma unroll
            for (int kc = 0; kc < 8; ++kc) {
                s16x8 bfrag = *(const s16x8*)(lbase + kc * 4096 + g * 1024 +
                                              (ct * 16 + cl) * 16);
                acc[0] = __builtin_amdgcn_mfma_f32_16x16x32_bf16(afrag[0][kc], bfrag, acc[0], 0, 0, 0);
                acc[1] = __builtin_amdgcn_mfma_f32_16x16x32_bf16(afrag[1][kc], bfrag, acc[1], 0, 0, 0);
            }
            #pragma unroll
            for (int rt = 0; rt < 2; ++rt)
                #pragma unroll
                for (int r = 0; r < 4; ++r)
                    pp[rt][r] += __builtin_amdgcn_exp2f(acc[rt][r]);
        }
        __syncthreads();   // drains vmcnt (next buf staged) + lgkmcnt (cur reads done)
    }

    // reduce across the 16 col-lanes (cl) within each g-group
    #pragma unroll
    for (int rt = 0; rt < 2; ++rt) {
        #pragma unroll
        for (int r = 0; r < 4; ++r) {
            float v = pp[rt][r];
            v += __shfl_xor(v, 1);
            v += __shfl_xor(v, 2);
            v += __shfl_xor(v, 4);
            v += __shfl_xor(v, 8);
            if (cl == 0)
                partial[(size_t)cc * N2 + rowbase + w * 32 + rt * 16 + g * 4 + r] = v;
        }
    }
}

// ---- K3: per-row loss, 32 blocks; block partial sums -> blocksum ----
__global__ __launch_bounds__(256) void k_loss(const float* __restrict__ partial,
                                              const float* __restrict__ diag,
                                              const float* __restrict__ posv,
                                              float* __restrict__ blocksum) {
    int row = blockIdx.x * 256 + threadIdx.x;
    float sum = 0.0f;
    #pragma unroll
    for (int c = 0; c < 16; ++c) sum += partial[(size_t)c * N2 + row];
    sum -= __builtin_amdgcn_exp2f(diag[row]);           // remove diagonal term
    float lr = __builtin_amdgcn_logf(sum) * LN2 - posv[row & (BROWS - 1)];
    lr = wave_reduce(lr);
    __shared__ float red[4];
    if ((threadIdx.x & 63) == 0) red[threadIdx.x >> 6] = lr;
    __syncthreads();
    if (threadIdx.x == 0)
        blocksum[blockIdx.x] = red[0] + red[1] + red[2] + red[3];
}

// ---- K4: final mean over 32 block sums ----
__global__ __launch_bounds__(64) void k_out(const float* __restrict__ blocksum,
                                            float* __restrict__ out) {
    int lane = threadIdx.x;
    float v = (lane < 32) ? blocksum[lane] : 0.0f;
    v = wave_reduce(v);
    if (lane == 0) out[0] = v * (1.0f / N2);
}

extern "C" void kernel_launch(void* const* d_in, const int* in_sizes, int n_in,
                              void* d_out, int out_size, void* d_ws, size_t ws_size,
                              hipStream_t stream) {
    const float* zi = (const float*)d_in[0];
    const float* zj = (const float*)d_in[1];
    float* out = (float*)d_out;

    char* ws = (char*)d_ws;
    unsigned short* zn = (unsigned short*)ws;                       // 4 MB
    float* diag        = (float*)(ws + (4u << 20));                 // 32 KB
    float* posv        = (float*)(ws + (4u << 20) + (32u << 10));   // 16 KB
    float* blocksum    = (float*)(ws + (4u << 20) + (48u << 10));   // 128 B
    float* partial     = (float*)(ws + (4u << 20) + (64u << 10));   // 512 KB

    k_norm_pos<<<BROWS / 4, 256, 0, stream>>>(zi, zj, zn, diag, posv);
    k_simsum<<<512, 512, 0, stream>>>(zn, partial);
    k_loss<<<32, 256, 0, stream>>>(partial, diag, posv, blocksum);
    k_out<<<1, 64, 0, stream>>>(blocksum, out);
}

// Round 3
// 53.509 us; speedup vs baseline: 3.1678x; 3.1678x over previous
//
#include <hip/hip_runtime.h>
#include <hip/hip_bf16.h>
#include <stdint.h>

// NT-Xent loss, B=4096, D=256, T=0.5, eps=1e-8.
// loss_r = log(sum_{c!=r} exp(2*dot(zn_r,zn_c))) - 2*dot(zin_r, zjn_r); out = mean.
// Trick: store zn_s = zn * sqrt(2*log2e) in bf16, so MFMA acc = 2*log2e*dot and
// exp(2*dot) = exp2(acc) directly. Diagonal accumulated unconditionally, subtracted
// in the finish kernel via exp2(diag) with diag = sum(zn_s_bf16^2) (exact bf16 self-dot).

#define BROWS 4096
#define DIM   256
#define N2    8192

typedef __attribute__((ext_vector_type(4))) float          f32x4;
typedef __attribute__((ext_vector_type(8))) short          s16x8;
typedef __attribute__((ext_vector_type(4))) unsigned short u16x4;

#define S_EXP  1.6986436597467051f   /* sqrt(2*log2(e)) */
#define LN2    0.6931471805599453f

__device__ inline unsigned short f2bf(float f) {
    uint32_t b = __float_as_uint(f);
    b += 0x7fffu + ((b >> 16) & 1u);   // RNE
    return (unsigned short)(b >> 16);
}
__device__ inline float bf2f(unsigned short u) {
    return __uint_as_float(((uint32_t)u) << 16);
}

__device__ inline void gload_lds16(const void* g, void* l) {
    __builtin_amdgcn_global_load_lds(
        (const __attribute__((address_space(1))) uint32_t*)g,
        (__attribute__((address_space(3))) uint32_t*)l, 16, 0, 0);
}

__device__ inline float wave_reduce(float v) {
    #pragma unroll
    for (int m = 1; m < 64; m <<= 1) v += __shfl_xor(v, m);
    return v;
}

// ---- K1: fused normalize (both views) + positive-pair exponent + diag self-dot ----
__global__ __launch_bounds__(256) void k_norm_pos(const float* __restrict__ zi,
                                                  const float* __restrict__ zj,
                                                  unsigned short* __restrict__ zn,
                                                  float* __restrict__ diag,
                                                  float* __restrict__ posv) {
    int i    = blockIdx.x * 4 + (threadIdx.x >> 6);
    int lane = threadIdx.x & 63;
    f32x4 a = *(const f32x4*)(zi + (size_t)i * DIM + lane * 4);
    f32x4 b = *(const f32x4*)(zj + (size_t)i * DIM + lane * 4);
    float ssa = a[0]*a[0] + a[1]*a[1] + a[2]*a[2] + a[3]*a[3];
    float ssb = b[0]*b[0] + b[1]*b[1] + b[2]*b[2] + b[3]*b[3];
    float dab = a[0]*b[0] + a[1]*b[1] + a[2]*b[2] + a[3]*b[3];
    ssa = wave_reduce(ssa);
    ssb = wave_reduce(ssb);
    dab = wave_reduce(dab);
    float na = 1.0f / fmaxf(sqrtf(ssa), 1e-8f);
    float nb = 1.0f / fmaxf(sqrtf(ssb), 1e-8f);
    if (lane == 0) posv[i] = 2.0f * dab * na * nb;   // natural-log exponent of pos pair

    float sa = na * S_EXP, sb = nb * S_EXP;
    u16x4 oa, ob;
    float da = 0.0f, db = 0.0f;
    #pragma unroll
    for (int k = 0; k < 4; ++k) {
        unsigned short ua = f2bf(a[k] * sa);
        unsigned short ub = f2bf(b[k] * sb);
        oa[k] = ua; ob[k] = ub;
        float fa = bf2f(ua), fb = bf2f(ub);
        da += fa * fa; db += fb * fb;
    }
    *(u16x4*)(zn + (size_t)i * DIM + lane * 4)           = oa;
    *(u16x4*)(zn + (size_t)(i + BROWS) * DIM + lane * 4) = ob;
    da = wave_reduce(da);
    db = wave_reduce(db);
    if (lane == 0) { diag[i] = da; diag[i + BROWS] = db; }
}

// ---- K2: fused sim GEMM + exp2 + row-sum (diagonal NOT masked) ----
// R1-proven geometry: 256 thr = 4 waves; 256 rows x 512 cols per block; grid 512.
// Wave owns 64 rows (4 row-tiles of 16), A-frags pinned (~128 regs, K=256).
// NEW: double-buffered LDS (2x32KB), next tile staged BEFORE compute phase.
// LDS layout: byte = buf*32768 + kc*4096 + g*1024 + col*16
//   holds zn[colbase + s*64 + col][kc*32 + g*8 .. +8]
__global__ __launch_bounds__(256, 2) void k_simsum(const unsigned short* __restrict__ zn,
                                                   float* __restrict__ partial) {
    __shared__ unsigned short lds[2][64 * DIM];   // 2 x 32 KB
    int bid = blockIdx.x;
    int rb = bid & 31;        // 32 row-blocks of 256
    int cc = bid >> 5;        // 16 col-chunks of 512
    int rowbase = rb * 256;
    int colbase = cc * 512;
    int tid = threadIdx.x, lane = tid & 63, w = tid >> 6;   // w in 0..3
    int cl = lane & 15, g = lane >> 4;

    // A fragments: lane holds zn[rowbase + w*64 + rt*16 + cl][kc*32 + g*8 .. +8]
    s16x8 afrag[4][8];
    #pragma unroll
    for (int rt = 0; rt < 4; ++rt) {
        int row = rowbase + w * 64 + rt * 16 + cl;
        const unsigned short* ap = zn + (size_t)row * DIM + g * 8;
        #pragma unroll
        for (int kc = 0; kc < 8; ++kc)
            afrag[rt][kc] = *(const s16x8*)(ap + kc * 32);
    }

    float pp[4][4];
    #pragma unroll
    for (int rt = 0; rt < 4; ++rt)
        #pragma unroll
        for (int r = 0; r < 4; ++r) pp[rt][r] = 0.0f;

    // stage 64 cols x 256 K into lds[buf]; 256 lanes x 16 B x 8 issues = 32 KB
    auto stage = [&](int buf, int s) {
        int crow = colbase + s * 64 + lane;
        const unsigned short* gsrc = zn + (size_t)crow * DIM;
        char* base = (char*)&lds[buf][0];
        #pragma unroll
        for (int i = 0; i < 8; ++i)
            gload_lds16(gsrc + i * 32 + w * 8, base + i * 4096 + w * 1024);
    };

    stage(0, 0);
    __syncthreads();   // prologue: buf0 ready

    for (int s = 0; s < 8; ++s) {
        int cur = s & 1;
        if (s < 7) stage(cur ^ 1, s + 1);   // issue next-tile loads BEFORE compute

        const char* lbase = (const char*)&lds[cur][0];
        #pragma unroll
        for (int ct = 0; ct < 4; ++ct) {
            f32x4 acc[4];
            #pragma unroll
            for (int rt = 0; rt < 4; ++rt) acc[rt] = (f32x4){0.f, 0.f, 0.f, 0.f};
            #pragma unroll
            for (int kc = 0; kc < 8; ++kc) {
                s16x8 bfrag = *(const s16x8*)(lbase + kc * 4096 + g * 1024 +
                                              (ct * 16 + cl) * 16);
                #pragma unroll
                for (int rt = 0; rt < 4; ++rt)
                    acc[rt] = __builtin_amdgcn_mfma_f32_16x16x32_bf16(
                                  afrag[rt][kc], bfrag, acc[rt], 0, 0, 0);
            }
            #pragma unroll
            for (int rt = 0; rt < 4; ++rt)
                #pragma unroll
                for (int r = 0; r < 4; ++r)
                    pp[rt][r] += __builtin_amdgcn_exp2f(acc[rt][r]);
        }
        __syncthreads();   // drains vmcnt (next buf staged) + lgkmcnt (cur reads done)
    }

    // reduce across the 16 col-lanes (cl) within each g-group
    #pragma unroll
    for (int rt = 0; rt < 4; ++rt) {
        #pragma unroll
        for (int r = 0; r < 4; ++r) {
            float v = pp[rt][r];
            v += __shfl_xor(v, 1);
            v += __shfl_xor(v, 2);
            v += __shfl_xor(v, 4);
            v += __shfl_xor(v, 8);
            if (cl == 0)
                partial[(size_t)cc * N2 + rowbase + w * 64 + rt * 16 + g * 4 + r] = v;
        }
    }
}

// ---- K3: single-block finish: rowsum -> loss -> mean ----
__global__ __launch_bounds__(1024) void k_finish(const float* __restrict__ partial,
                                                 const float* __restrict__ diag,
                                                 const float* __restrict__ posv,
                                                 float* __restrict__ out) {
    int tid = threadIdx.x;
    float local = 0.0f;
    for (int r = tid; r < N2; r += 1024) {
        float sum = 0.0f;
        #pragma unroll
        for (int c = 0; c < 16; ++c) sum += partial[(size_t)c * N2 + r];
        sum -= __builtin_amdgcn_exp2f(diag[r]);           // remove diagonal term
        local += __builtin_amdgcn_logf(sum) * LN2 - posv[r & (BROWS - 1)];
    }
    local = wave_reduce(local);
    __shared__ float red[16];
    if ((tid & 63) == 0) red[tid >> 6] = local;
    __syncthreads();
    if (tid == 0) {
        float t = 0.0f;
        #pragma unroll
        for (int i = 0; i < 16; ++i) t += red[i];
        out[0] = t * (1.0f / N2);
    }
}

extern "C" void kernel_launch(void* const* d_in, const int* in_sizes, int n_in,
                              void* d_out, int out_size, void* d_ws, size_t ws_size,
                              hipStream_t stream) {
    const float* zi = (const float*)d_in[0];
    const float* zj = (const float*)d_in[1];
    float* out = (float*)d_out;

    char* ws = (char*)d_ws;
    unsigned short* zn = (unsigned short*)ws;                       // 4 MB
    float* diag        = (float*)(ws + (4u << 20));                 // 32 KB
    float* posv        = (float*)(ws + (4u << 20) + (32u << 10));   // 16 KB
    float* partial     = (float*)(ws + (4u << 20) + (64u << 10));   // 512 KB

    k_norm_pos<<<BROWS / 4, 256, 0, stream>>>(zi, zj, zn, diag, posv);
    k_simsum<<<512, 256, 0, stream>>>(zn, partial);
    k_finish<<<1, 1024, 0, stream>>>(partial, diag, posv, out);
}